// Round 1
// baseline (440.199 us; speedup 1.0000x reference)
//
#include <hip/hip_runtime.h>

#define EPS 1e-12f
constexpr int NB = 64;    // batches
constexpr int NP = 1024;  // pixels per batch (H*W)
constexpr int ND = 512;   // feature dim
constexpr int NK = 64;    // clusters

// ---------------------------------------------------------------------------
// Kernel A: s = x@w per pixel, softmax over K -> a_buf; per-batch asum via
// atomics. Block = 256 thr, tile = 128 px x 64 k. Thread tile 8px x 4k.
// w slab staged in LDS (read as b128, 4k per read, amortized over 8 px);
// x read from global (L1-hot, 16-way lane broadcast).
// ---------------------------------------------------------------------------
extern "C" __global__ __launch_bounds__(256) void netvlad_assign(
    const float* __restrict__ x, const float* __restrict__ w,
    float* __restrict__ a_buf, float* __restrict__ asum)
{
  __shared__ float ws[32 * 64];   // w slab [dd][k]
  __shared__ float asp[16 * 64];  // asum partials [ti][k]
  const int t  = threadIdx.x;
  const int tj = t & 15;   // k-group: k = tj*4 .. +4
  const int ti = t >> 4;   // px-group: px = ti*8 .. +8
  const int b  = blockIdx.x >> 3;
  const int pt = blockIdx.x & 7;
  const float* xb = x + (size_t)(b * NP + pt * 128) * ND;

  float acc[8][4];
#pragma unroll
  for (int p = 0; p < 8; ++p)
#pragma unroll
    for (int j = 0; j < 4; ++j) acc[p][j] = 0.f;

  float4* ws4 = (float4*)ws;
  for (int d0 = 0; d0 < ND; d0 += 32) {
    __syncthreads();
    const float4* wg = (const float4*)(w + (size_t)d0 * NK);
    ws4[t]       = wg[t];
    ws4[t + 256] = wg[t + 256];
    __syncthreads();
#pragma unroll
    for (int dd = 0; dd < 32; dd += 4) {
      float wq[4][4];
#pragma unroll
      for (int jj = 0; jj < 4; ++jj) {
        float4 wv = ws4[(dd + jj) * 16 + tj];
        wq[jj][0] = wv.x; wq[jj][1] = wv.y; wq[jj][2] = wv.z; wq[jj][3] = wv.w;
      }
#pragma unroll
      for (int p = 0; p < 8; ++p) {
        float4 xv = *(const float4*)(xb + (size_t)(ti * 8 + p) * ND + d0 + dd);
        float xq[4] = {xv.x, xv.y, xv.z, xv.w};
#pragma unroll
        for (int jj = 0; jj < 4; ++jj)
#pragma unroll
          for (int j = 0; j < 4; ++j)
            acc[p][j] = fmaf(xq[jj], wq[jj][j], acc[p][j]);
      }
    }
  }

  // softmax over k: thread has 4 k's; 16 lanes (tj) cover all 64 k.
  float asum_acc[4] = {0.f, 0.f, 0.f, 0.f};
  float* ab = a_buf + (size_t)(b * NP + pt * 128) * NK;
#pragma unroll
  for (int p = 0; p < 8; ++p) {
    float m = fmaxf(fmaxf(acc[p][0], acc[p][1]), fmaxf(acc[p][2], acc[p][3]));
    m = fmaxf(m, __shfl_xor(m, 1));
    m = fmaxf(m, __shfl_xor(m, 2));
    m = fmaxf(m, __shfl_xor(m, 4));
    m = fmaxf(m, __shfl_xor(m, 8));
    float e[4]; float s = 0.f;
#pragma unroll
    for (int j = 0; j < 4; ++j) { e[j] = __expf(acc[p][j] - m); s += e[j]; }
    s += __shfl_xor(s, 1);
    s += __shfl_xor(s, 2);
    s += __shfl_xor(s, 4);
    s += __shfl_xor(s, 8);
    float inv = 1.0f / s;
    float4 av;
    av.x = e[0] * inv; av.y = e[1] * inv; av.z = e[2] * inv; av.w = e[3] * inv;
    asum_acc[0] += av.x; asum_acc[1] += av.y;
    asum_acc[2] += av.z; asum_acc[3] += av.w;
    *(float4*)(ab + (size_t)(ti * 8 + p) * NK + tj * 4) = av;
  }
  ((float4*)asp)[ti * 16 + tj] =
      make_float4(asum_acc[0], asum_acc[1], asum_acc[2], asum_acc[3]);
  __syncthreads();
  if (t < 64) {
    float s = 0.f;
#pragma unroll
    for (int g = 0; g < 16; ++g) s += asp[g * 64 + t];
    atomicAdd(&asum[b * NK + t], s);
  }
}

// ---------------------------------------------------------------------------
// Kernel B: per-batch vkd_p[nh][b][d][k] = sum_{n in half} a[n][k]*x[n][d]
// (raw partial, written TRANSPOSED to [d][k] so the epilogue is coalesced).
// Block = 256 thr, tile = 64 k x 128 d x 512 n-half. Thread tile 4k x 8d.
// a slab staged in LDS (b128), x from global float4.
// ---------------------------------------------------------------------------
extern "C" __global__ __launch_bounds__(256) void netvlad_vlad(
    const float* __restrict__ x, const float* __restrict__ a_buf,
    float* __restrict__ vkd_p)
{
  __shared__ float as[64 * 64];  // a slab [nn][k]
  const int t  = threadIdx.x;
  const int tk = t & 15;   // k = tk*4 .. +4
  const int td = t >> 4;   // d-sub = td*8 .. +8
  const int b    = blockIdx.x >> 3;
  const int dblk = (blockIdx.x >> 1) & 3;
  const int nh   = blockIdx.x & 1;
  const float* xb = x + (size_t)(b * NP + nh * 512) * ND + dblk * 128 + td * 8;
  const float* ab = a_buf + (size_t)(b * NP + nh * 512) * NK;
  float4* as4 = (float4*)as;

  float acc[8][4];
#pragma unroll
  for (int dj = 0; dj < 8; ++dj)
#pragma unroll
    for (int j = 0; j < 4; ++j) acc[dj][j] = 0.f;

  for (int slab = 0; slab < 8; ++slab) {
    __syncthreads();
    const float4* ag = (const float4*)(ab + (size_t)slab * 64 * NK);
#pragma unroll
    for (int c = 0; c < 4; ++c) as4[t + 256 * c] = ag[t + 256 * c];
    __syncthreads();
#pragma unroll 4
    for (int nn = 0; nn < 64; ++nn) {
      float4 a4 = as4[nn * 16 + tk];
      const float* xr = xb + (size_t)(slab * 64 + nn) * ND;
      float4 x0 = *(const float4*)(xr);
      float4 x1 = *(const float4*)(xr + 4);
      float xq[8] = {x0.x, x0.y, x0.z, x0.w, x1.x, x1.y, x1.z, x1.w};
      float aq[4] = {a4.x, a4.y, a4.z, a4.w};
#pragma unroll
      for (int dj = 0; dj < 8; ++dj)
#pragma unroll
        for (int j = 0; j < 4; ++j)
          acc[dj][j] = fmaf(xq[dj], aq[j], acc[dj][j]);
    }
  }
  float* vb = vkd_p + ((size_t)((nh * NB + b) * ND + dblk * 128 + td * 8)) * NK
            + tk * 4;
#pragma unroll
  for (int dj = 0; dj < 8; ++dj)
    *(float4*)(vb + (size_t)dj * NK) =
        make_float4(acc[dj][0], acc[dj][1], acc[dj][2], acc[dj][3]);
}

// ---------------------------------------------------------------------------
// Kernel C1: v = p0 + p1 + asum[k]*C[d][k]; write raw v to out[b][d][k];
// accumulate r_k = sum_d v^2 partials -> r_buf atomics. All accesses are
// k-contiguous (coalesced 256 B rows).
// ---------------------------------------------------------------------------
extern "C" __global__ __launch_bounds__(256) void netvlad_fin1(
    const float* __restrict__ vkd_p, const float* __restrict__ Cm,
    const float* __restrict__ asum, float* __restrict__ out,
    float* __restrict__ r_buf)
{
  __shared__ float rp[4 * 64];
  const int t  = threadIdx.x;
  const int k  = t & 63;
  const int dg = t >> 6;
  const int b  = blockIdx.x >> 2;
  const int dq = blockIdx.x & 3;
  const float asv = asum[b * NK + k];
  const int dbase = dq * 128 + dg * 32;
  const float* p0 = vkd_p + (size_t)b * ND * NK;
  const float* p1 = vkd_p + (size_t)(NB + b) * ND * NK;
  float* ob = out + (size_t)b * ND * NK;
  float racc = 0.f;
  for (int dd = 0; dd < 32; ++dd) {
    int d = dbase + dd;
    size_t off = (size_t)d * NK + k;
    float v = p0[off] + p1[off] + asv * Cm[off];
    ob[off] = v;
    racc = fmaf(v, v, racc);
  }
  rp[dg * 64 + k] = racc;
  __syncthreads();
  if (t < 64) {
    float r = rp[t] + rp[64 + t] + rp[128 + t] + rp[192 + t];
    atomicAdd(&r_buf[b * NK + t], r);
  }
}

// ---------------------------------------------------------------------------
// Kernel C2: per batch, g = sum_k r/(r+eps)  (exact norm of intra-normalized
// rows), scale_k = 1/(sqrt(r+eps)*sqrt(g+eps)). One wave per batch.
// ---------------------------------------------------------------------------
extern "C" __global__ __launch_bounds__(64) void netvlad_fin2(
    const float* __restrict__ r_buf, float* __restrict__ scale_buf)
{
  const int b = blockIdx.x;
  const int k = threadIdx.x;
  float r = r_buf[b * NK + k];
  float g = r / (r + EPS);
  g += __shfl_xor(g, 1);
  g += __shfl_xor(g, 2);
  g += __shfl_xor(g, 4);
  g += __shfl_xor(g, 8);
  g += __shfl_xor(g, 16);
  g += __shfl_xor(g, 32);
  scale_buf[b * NK + k] = 1.0f / (sqrtf(r + EPS) * sqrtf(g + EPS));
}

// ---------------------------------------------------------------------------
// Kernel C3: out *= scale[k] in place, fully coalesced float4.
// ---------------------------------------------------------------------------
extern "C" __global__ __launch_bounds__(256) void netvlad_fin3(
    float* __restrict__ out, const float* __restrict__ scale_buf)
{
  __shared__ float sc[64];
  const int t = threadIdx.x;
  const int b = blockIdx.x >> 3;
  if (t < 64) sc[t] = scale_buf[b * NK + t];
  __syncthreads();
  float4* o4 = (float4*)out;
#pragma unroll
  for (int c = 0; c < 4; ++c) {
    int idx = blockIdx.x * 1024 + c * 256 + t;
    float4 v = o4[idx];
    int k4 = (idx & 15) * 4;
    v.x *= sc[k4]; v.y *= sc[k4 + 1]; v.z *= sc[k4 + 2]; v.w *= sc[k4 + 3];
    o4[idx] = v;
  }
}

// ---------------------------------------------------------------------------
extern "C" void kernel_launch(void* const* d_in, const int* in_sizes, int n_in,
                              void* d_out, int out_size, void* d_ws,
                              size_t ws_size, hipStream_t stream)
{
  const float* x  = (const float*)d_in[0];  // [64,32,32,512]
  const float* w  = (const float*)d_in[1];  // [512,64]
  const float* Cm = (const float*)d_in[2];  // [512,64]
  float* out = (float*)d_out;               // [64, 512*64]
  float* wsf = (float*)d_ws;

  // workspace carve (floats): total 8,400,896 floats = 33.6 MB
  float* a_buf     = wsf;                  // 64*1024*64  = 4,194,304
  float* vkd_p     = wsf + 4194304;        // 2*64*512*64 = 4,194,304
  float* asum      = wsf + 8388608;        // 4096
  float* r_buf     = wsf + 8392704;        // 4096
  float* scale_buf = wsf + 8396800;        // 4096

  hipMemsetAsync(asum, 0, 4096 * sizeof(float), stream);
  hipMemsetAsync(r_buf, 0, 4096 * sizeof(float), stream);

  netvlad_assign<<<512, 256, 0, stream>>>(x, w, a_buf, asum);
  netvlad_vlad  <<<512, 256, 0, stream>>>(x, a_buf, vkd_p);
  netvlad_fin1  <<<256, 256, 0, stream>>>(vkd_p, Cm, asum, out, r_buf);
  netvlad_fin2  <<< 64,  64, 0, stream>>>(r_buf, scale_buf);
  netvlad_fin3  <<<512, 256, 0, stream>>>(out, scale_buf);
}

// Round 3
// 305.996 us; speedup vs baseline: 1.4386x; 1.4386x over previous
//
#include <hip/hip_runtime.h>

#define EPS 1e-12f
typedef __attribute__((ext_vector_type(8))) short short8;   // 8 x bf16
typedef __attribute__((ext_vector_type(4))) float f32x4;    // MFMA acc

// ---- bf16 split helpers -------------------------------------------------
__device__ __forceinline__ unsigned short f2bf(float f) {
  unsigned u = __float_as_uint(f);
  u += 0x7FFFu + ((u >> 16) & 1u);          // RNE
  return (unsigned short)(u >> 16);
}
__device__ __forceinline__ float bf2f(unsigned short h) {
  return __uint_as_float(((unsigned)h) << 16);
}
__device__ __forceinline__ void split2(float f, unsigned short& h,
                                       unsigned short& l) {
  h = f2bf(f);
  l = f2bf(f - bf2f(h));
}

// ---------------------------------------------------------------------------
// Prep: w [512 d][64 k] fp32 -> wT hi/lo bf16 [64 k][512 d]
// ---------------------------------------------------------------------------
extern "C" __global__ __launch_bounds__(256) void netvlad_prep(
    const float* __restrict__ w, unsigned short* __restrict__ wTh,
    unsigned short* __restrict__ wTl)
{
  int tg = blockIdx.x * 256 + threadIdx.x;   // 0..32767 ; = k*512 + d
  int k = tg >> 9, d = tg & 511;
  float f = w[d * 64 + k];
  unsigned short h, l;
  split2(f, h, l);
  wTh[tg] = h;
  wTl[tg] = l;
}

// ---------------------------------------------------------------------------
// Kernel A: s = x@w (MFMA bf16-split), softmax over K, emit aT hi/lo bf16
// [b][64 k][1024 n] + asum. Block 256 thr / 4 waves = 64 px; grid 1024.
// ---------------------------------------------------------------------------
extern "C" __global__ __launch_bounds__(256) void netvlad_assign(
    const float* __restrict__ x, const unsigned short* __restrict__ wTh,
    const unsigned short* __restrict__ wTl, unsigned short* __restrict__ aTh,
    unsigned short* __restrict__ aTl, float* __restrict__ asum)
{
  __shared__ unsigned short xh[64 * 40];   // [px][d] pad 40 (80 B rows)
  __shared__ unsigned short xl[64 * 40];
  __shared__ unsigned short ath[64 * 80];  // aT tile [k][px] pad 80 (160 B)
  __shared__ unsigned short atl[64 * 80];
  __shared__ float asp[4 * 64];

  const int t = threadIdx.x;
  const int lane = t & 63, wv = t >> 6;
  const int lo4 = lane & 15, hi4 = lane >> 4;
  const int pxblk = blockIdx.x << 6;          // global pixel base
  const int b = blockIdx.x >> 4;
  const int nblk = (blockIdx.x & 15) << 6;    // pixel base within batch

  f32x4 acc[4] = {{0.f, 0.f, 0.f, 0.f}, {0.f, 0.f, 0.f, 0.f},
                  {0.f, 0.f, 0.f, 0.f}, {0.f, 0.f, 0.f, 0.f}};

  const int spx = t >> 2;            // staging row 0..63
  const int sd = (t & 3) * 8;        // staging col 0/8/16/24
  const float* xrow = x + (size_t)(pxblk + spx) * 512 + sd;

  for (int d0 = 0; d0 < 512; d0 += 32) {
    __syncthreads();
    float4 v0 = *(const float4*)(xrow + d0);
    float4 v1 = *(const float4*)(xrow + d0 + 4);
    ushort4 h0, h1, l0, l1;
    split2(v0.x, h0.x, l0.x); split2(v0.y, h0.y, l0.y);
    split2(v0.z, h0.z, l0.z); split2(v0.w, h0.w, l0.w);
    split2(v1.x, h1.x, l1.x); split2(v1.y, h1.y, l1.y);
    split2(v1.z, h1.z, l1.z); split2(v1.w, h1.w, l1.w);
    *(ushort4*)&xh[spx * 40 + sd] = h0;
    *(ushort4*)&xh[spx * 40 + sd + 4] = h1;
    *(ushort4*)&xl[spx * 40 + sd] = l0;
    *(ushort4*)&xl[spx * 40 + sd + 4] = l1;
    __syncthreads();

    short8 xfh = *(short8*)&xh[(wv * 16 + lo4) * 40 + hi4 * 8];
    short8 xfl = *(short8*)&xl[(wv * 16 + lo4) * 40 + hi4 * 8];
#pragma unroll
    for (int nt = 0; nt < 4; ++nt) {
      const size_t wo = (size_t)(nt * 16 + lo4) * 512 + d0 + hi4 * 8;
      short8 wfh = *(const short8*)(wTh + wo);
      short8 wfl = *(const short8*)(wTl + wo);
      acc[nt] = __builtin_amdgcn_mfma_f32_16x16x32_bf16(xfh, wfh, acc[nt], 0, 0, 0);
      acc[nt] = __builtin_amdgcn_mfma_f32_16x16x32_bf16(xfl, wfh, acc[nt], 0, 0, 0);
      acc[nt] = __builtin_amdgcn_mfma_f32_16x16x32_bf16(xfh, wfl, acc[nt], 0, 0, 0);
    }
  }

  // softmax over k (64 = 4 nt regs x 16 lanes of lo4); px = wv*16+hi4*4+r
  float asum_p[4] = {0.f, 0.f, 0.f, 0.f};
#pragma unroll
  for (int r = 0; r < 4; ++r) {
    float s0 = acc[0][r], s1 = acc[1][r], s2 = acc[2][r], s3 = acc[3][r];
    float m = fmaxf(fmaxf(s0, s1), fmaxf(s2, s3));
    m = fmaxf(m, __shfl_xor(m, 1));
    m = fmaxf(m, __shfl_xor(m, 2));
    m = fmaxf(m, __shfl_xor(m, 4));
    m = fmaxf(m, __shfl_xor(m, 8));
    float e0 = __expf(s0 - m), e1 = __expf(s1 - m);
    float e2 = __expf(s2 - m), e3 = __expf(s3 - m);
    float s = e0 + e1 + e2 + e3;
    s += __shfl_xor(s, 1);
    s += __shfl_xor(s, 2);
    s += __shfl_xor(s, 4);
    s += __shfl_xor(s, 8);
    float inv = 1.0f / s;
    e0 *= inv; e1 *= inv; e2 *= inv; e3 *= inv;
    asum_p[0] += e0; asum_p[1] += e1; asum_p[2] += e2; asum_p[3] += e3;
    const int px = wv * 16 + hi4 * 4 + r;
    unsigned short h, l;
    split2(e0, h, l); ath[(0 * 16 + lo4) * 80 + px] = h; atl[(0 * 16 + lo4) * 80 + px] = l;
    split2(e1, h, l); ath[(1 * 16 + lo4) * 80 + px] = h; atl[(1 * 16 + lo4) * 80 + px] = l;
    split2(e2, h, l); ath[(2 * 16 + lo4) * 80 + px] = h; atl[(2 * 16 + lo4) * 80 + px] = l;
    split2(e3, h, l); ath[(3 * 16 + lo4) * 80 + px] = h; atl[(3 * 16 + lo4) * 80 + px] = l;
  }
#pragma unroll
  for (int nt = 0; nt < 4; ++nt) {
    float v = asum_p[nt];
    v += __shfl_xor(v, 16);
    v += __shfl_xor(v, 32);
    if (lane < 16) asp[wv * 64 + nt * 16 + lane] = v;
  }
  __syncthreads();
  if (t < 64) {
    float s = asp[t] + asp[64 + t] + asp[128 + t] + asp[192 + t];
    atomicAdd(&asum[b * 64 + t], s);
  }
  // cooperative coalesced store of aT tiles: 64 k x 64 px.
  // thread t -> k = t>>2, px quarter q = t&3 -> px [q*16, q*16+16).
  {
    const int k = t >> 2, po = (t & 3) * 16;
    short8 h0 = *(short8*)&ath[k * 80 + po];
    short8 h1 = *(short8*)&ath[k * 80 + po + 8];
    short8 l0 = *(short8*)&atl[k * 80 + po];
    short8 l1 = *(short8*)&atl[k * 80 + po + 8];
    const size_t go = ((size_t)(b * 64 + k) << 10) + nblk + po;
    *(short8*)(aTh + go) = h0;
    *(short8*)(aTh + go + 8) = h1;
    *(short8*)(aTl + go) = l0;
    *(short8*)(aTl + go + 8) = l1;
  }
}

// ---------------------------------------------------------------------------
// Kernel B: vkd[b][d][k] = sum_n aT[k][n]*x[n][d] (MFMA bf16-split).
// Block 256 thr / 4 waves: full 64 k x 32 d slice, n = 1024 (32 steps of 32).
// Grid = 64 b x 16 dslices = 1024. x transposed into LDS per step.
// ---------------------------------------------------------------------------
extern "C" __global__ __launch_bounds__(256) void netvlad_vlad(
    const float* __restrict__ x, const unsigned short* __restrict__ aTh,
    const unsigned short* __restrict__ aTl, float* __restrict__ vkd)
{
  __shared__ unsigned short xth[32 * 40];   // xT [d][n] pad 40 (80 B rows)
  __shared__ unsigned short xtl[32 * 40];
  const int t = threadIdx.x;
  const int lane = t & 63, wv = t >> 6;
  const int lo4 = lane & 15, hi4 = lane >> 4;
  const int b = blockIdx.x >> 4;
  const int ds = (blockIdx.x & 15) << 5;    // d-slice base
  const int np = (t & 15) * 2;              // staging n-pair
  const int sdd = (t >> 4) * 2;             // staging d (0..30 even)
  const float* xs = x + (size_t)b * 1024 * 512 + ds;

  f32x4 acc[2] = {{0.f, 0.f, 0.f, 0.f}, {0.f, 0.f, 0.f, 0.f}};

  for (int n0 = 0; n0 < 1024; n0 += 32) {
    __syncthreads();
    float2 u = *(const float2*)(xs + (size_t)(n0 + np) * 512 + sdd);
    float2 v = *(const float2*)(xs + (size_t)(n0 + np + 1) * 512 + sdd);
    ushort2 h0, h1, l0, l1;
    split2(u.x, h0.x, l0.x); split2(v.x, h0.y, l0.y);   // col n, n+1 @ row sdd
    split2(u.y, h1.x, l1.x); split2(v.y, h1.y, l1.y);   // row sdd+1
    *(ushort2*)&xth[sdd * 40 + np] = h0;
    *(ushort2*)&xth[(sdd + 1) * 40 + np] = h1;
    *(ushort2*)&xtl[sdd * 40 + np] = l0;
    *(ushort2*)&xtl[(sdd + 1) * 40 + np] = l1;
    __syncthreads();

    const size_t ao = (size_t)(b * 64 + wv * 16 + lo4) * 1024 + n0 + hi4 * 8;
    short8 ah = *(const short8*)(aTh + ao);
    short8 al = *(const short8*)(aTl + ao);
#pragma unroll
    for (int dt = 0; dt < 2; ++dt) {
      short8 bh = *(short8*)&xth[(dt * 16 + lo4) * 40 + hi4 * 8];
      short8 bl = *(short8*)&xtl[(dt * 16 + lo4) * 40 + hi4 * 8];
      acc[dt] = __builtin_amdgcn_mfma_f32_16x16x32_bf16(ah, bh, acc[dt], 0, 0, 0);
      acc[dt] = __builtin_amdgcn_mfma_f32_16x16x32_bf16(ah, bl, acc[dt], 0, 0, 0);
      acc[dt] = __builtin_amdgcn_mfma_f32_16x16x32_bf16(al, bh, acc[dt], 0, 0, 0);
    }
  }
  // D: row k = wv*16 + hi4*4 + r, col d = ds + dt*16 + lo4
#pragma unroll
  for (int dt = 0; dt < 2; ++dt) {
    float* vb = vkd + ((size_t)(b * 512 + ds + dt * 16 + lo4)) * 64
              + wv * 16 + hi4 * 4;
    *(float4*)vb = make_float4(acc[dt][0], acc[dt][1], acc[dt][2], acc[dt][3]);
  }
}

// ---------------------------------------------------------------------------
// Kernel C1: v = vkd + asum[k]*C[d][k]; write out[b][d][k]; r_k partials.
// ---------------------------------------------------------------------------
extern "C" __global__ __launch_bounds__(256) void netvlad_fin1(
    const float* __restrict__ vkd, const float* __restrict__ Cm,
    const float* __restrict__ asum, float* __restrict__ out,
    float* __restrict__ r_buf)
{
  __shared__ float rp[4 * 64];
  const int t = threadIdx.x;
  const int k = t & 63;
  const int dg = t >> 6;
  const int b = blockIdx.x >> 2;
  const int dq = blockIdx.x & 3;
  const float asv = asum[b * 64 + k];
  const int dbase = dq * 128 + dg * 32;
  const float* p0 = vkd + (size_t)b * 512 * 64;
  float* ob = out + (size_t)b * 512 * 64;
  float racc = 0.f;
  for (int dd = 0; dd < 32; ++dd) {
    size_t off = (size_t)(dbase + dd) * 64 + k;
    float v = p0[off] + asv * Cm[off];
    ob[off] = v;
    racc = fmaf(v, v, racc);
  }
  rp[dg * 64 + k] = racc;
  __syncthreads();
  if (t < 64) {
    float r = rp[t] + rp[64 + t] + rp[128 + t] + rp[192 + t];
    atomicAdd(&r_buf[b * 64 + t], r);
  }
}

// ---------------------------------------------------------------------------
extern "C" __global__ __launch_bounds__(64) void netvlad_fin2(
    const float* __restrict__ r_buf, float* __restrict__ scale_buf)
{
  const int b = blockIdx.x;
  const int k = threadIdx.x;
  float r = r_buf[b * 64 + k];
  float g = r / (r + EPS);
  g += __shfl_xor(g, 1);
  g += __shfl_xor(g, 2);
  g += __shfl_xor(g, 4);
  g += __shfl_xor(g, 8);
  g += __shfl_xor(g, 16);
  g += __shfl_xor(g, 32);
  scale_buf[b * 64 + k] = 1.0f / (sqrtf(r + EPS) * sqrtf(g + EPS));
}

// ---------------------------------------------------------------------------
extern "C" __global__ __launch_bounds__(256) void netvlad_fin3(
    float* __restrict__ out, const float* __restrict__ scale_buf)
{
  __shared__ float sc[64];
  const int t = threadIdx.x;
  const int b = blockIdx.x >> 3;
  if (t < 64) sc[t] = scale_buf[b * 64 + t];
  __syncthreads();
  float4* o4 = (float4*)out;
#pragma unroll
  for (int c = 0; c < 4; ++c) {
    int idx = blockIdx.x * 1024 + c * 256 + t;
    float4 v = o4[idx];
    int k4 = (idx & 15) * 4;
    v.x *= sc[k4]; v.y *= sc[k4 + 1]; v.z *= sc[k4 + 2]; v.w *= sc[k4 + 3];
    o4[idx] = v;
  }
}

// ---------------------------------------------------------------------------
extern "C" void kernel_launch(void* const* d_in, const int* in_sizes, int n_in,
                              void* d_out, int out_size, void* d_ws,
                              size_t ws_size, hipStream_t stream)
{
  const float* x  = (const float*)d_in[0];  // [64,32,32,512]
  const float* w  = (const float*)d_in[1];  // [512,64]
  const float* Cm = (const float*)d_in[2];  // [512,64]
  float* out = (float*)d_out;               // [64, 512*64]

  // workspace carve: 25.4 MB total
  unsigned short* aTh = (unsigned short*)d_ws;          // 64*64*1024 u16 = 8 MiB
  unsigned short* aTl = aTh + 4194304;                  // 8 MiB
  float* vkd = (float*)(aTl + 4194304);                 // 64*512*64 f32 = 8 MiB
  unsigned short* wTh = (unsigned short*)(vkd + 2097152); // 64 KiB
  unsigned short* wTl = wTh + 32768;                    // 64 KiB
  float* asum = (float*)(wTl + 32768);                  // 16 KiB
  float* r_buf = asum + 4096;                           // 16 KiB
  float* scale_buf = r_buf + 4096;                      // 16 KiB

  hipMemsetAsync(asum, 0, 2 * 4096 * sizeof(float), stream);  // asum + r_buf

  netvlad_prep  <<< 128, 256, 0, stream>>>(w, wTh, wTl);
  netvlad_assign<<<1024, 256, 0, stream>>>(x, wTh, wTl, aTh, aTl, asum);
  netvlad_vlad  <<<1024, 256, 0, stream>>>(x, aTh, aTl, vkd);
  netvlad_fin1  <<< 256, 256, 0, stream>>>(vkd, Cm, asum, out, r_buf);
  netvlad_fin2  <<<  64,  64, 0, stream>>>(r_buf, scale_buf);
  netvlad_fin3  <<< 512, 256, 0, stream>>>(out, scale_buf);
}